// Round 3
// baseline (716.794 us; speedup 1.0000x reference)
//
#include <hip/hip_runtime.h>

#define BB 32
#define SS 4096
#define DD 1024
#define OO 1024
#define KK 2048
#define RAD 64
#define NSPLIT 8

// ---- Kernel 1: score[b,s] = dot(src[b,s,:], tgt[b,:]) ----
// grid (S/16, B), 256 threads = 4 waves, 4 s per wave. Lane l covers
// elements [4l..4l+3] + 3 more float4 strides (16 floats = 64 B/lane/row).
__global__ __launch_bounds__(256) void k_score(const float* __restrict__ src,
                                               const float* __restrict__ tgt,
                                               float* __restrict__ score) {
  const int b = blockIdx.y;
  const int wave = threadIdx.x >> 6;
  const int lane = threadIdx.x & 63;
  const int s_base = blockIdx.x * 16 + wave * 4;
  const float4* tv = (const float4*)(tgt + (size_t)b * DD);
  float4 q0 = tv[lane], q1 = tv[64 + lane], q2 = tv[128 + lane], q3 = tv[192 + lane];
  for (int i = 0; i < 4; ++i) {
    const int s = s_base + i;
    const float4* rv = (const float4*)(src + ((size_t)b * SS + s) * DD);
    float4 a0 = rv[lane], a1 = rv[64 + lane], a2 = rv[128 + lane], a3 = rv[192 + lane];
    float p = 0.f;
    p += a0.x*q0.x + a0.y*q0.y + a0.z*q0.z + a0.w*q0.w;
    p += a1.x*q1.x + a1.y*q1.y + a1.z*q1.z + a1.w*q1.w;
    p += a2.x*q2.x + a2.y*q2.y + a2.z*q2.z + a2.w*q2.w;
    p += a3.x*q3.x + a3.y*q3.y + a3.z*q3.z + a3.w*q3.w;
    for (int off = 32; off > 0; off >>= 1) p += __shfl_xor(p, off);
    if (lane == 0) score[(size_t)b * SS + s] = p;
  }
}

// ---- Kernel 2: per-batch softmax stats (max, denom) ----
__global__ __launch_bounds__(256) void k_stats(const float* __restrict__ score,
                                               float* __restrict__ stats) {
  const int b = blockIdx.x;
  __shared__ float red[256];
  const float* sc = score + (size_t)b * SS;
  float m = -1e30f;
  for (int t = threadIdx.x; t < SS; t += 256) m = fmaxf(m, sc[t]);
  red[threadIdx.x] = m; __syncthreads();
  for (int off = 128; off > 0; off >>= 1) {
    if (threadIdx.x < off) red[threadIdx.x] = fmaxf(red[threadIdx.x], red[threadIdx.x + off]);
    __syncthreads();
  }
  m = red[0]; __syncthreads();
  float s = 0.f;
  for (int t = threadIdx.x; t < SS; t += 256) s += expf(sc[t] - m);
  red[threadIdx.x] = s; __syncthreads();
  for (int off = 128; off > 0; off >>= 1) {
    if (threadIdx.x < off) red[threadIdx.x] += red[threadIdx.x + off];
    __syncthreads();
  }
  if (threadIdx.x == 0) { stats[2 * b] = m; stats[2 * b + 1] = red[0]; }
}

// ---- Kernel 3: windowed weighted sum ----
// pos_w = exp(-rel^2/128) < 1e-14 beyond |rel|=64 -> window [pos-64, pos+64].
// grid (NSPLIT, B); thread t covers d = 4t..4t+3; partial[split][b][d].
__global__ __launch_bounds__(256) void k_weighted(const float* __restrict__ src,
                                                  const float* __restrict__ score,
                                                  const float* __restrict__ stats,
                                                  const int* __restrict__ pos,
                                                  float* __restrict__ partial) {
  const int b = blockIdx.y;
  const int split = blockIdx.x;
  const int p = pos[b];
  int w0 = p - RAD; if (w0 < 0) w0 = 0;
  int w1 = p + RAD + 1; if (w1 > SS) w1 = SS;
  const int len = w1 - w0;
  const int chunk = (len + NSPLIT - 1) / NSPLIT;
  int cs = w0 + split * chunk;
  int ce = cs + chunk; if (ce > w1) ce = w1;
  const float m = stats[2 * b];
  const float inv = 1.f / stats[2 * b + 1];
  const int t = threadIdx.x;
  float a0 = 0.f, a1 = 0.f, a2 = 0.f, a3 = 0.f;
  for (int s = cs; s < ce; ++s) {
    float rel = (float)(s - p);
    float w = expf(score[(size_t)b * SS + s] - m) * inv * expf(rel * rel * (-1.f / 128.f));
    float4 v = ((const float4*)(src + ((size_t)b * SS + s) * DD))[t];
    a0 += w * v.x; a1 += w * v.y; a2 += w * v.z; a3 += w * v.w;
  }
  float4* outp = (float4*)(partial + ((size_t)split * BB + b) * DD);
  outp[t] = make_float4(a0, a1, a2, a3);  // always write: ws is re-poisoned
}

// ---- Kernel 4: out[b,o] = tanh( [tgt, weighted] @ W ) ----
// grid (O/128, B); 256 threads = 4 k-quarter waves x 64 o-pair lanes.
__global__ __launch_bounds__(256) void k_out(const float* __restrict__ tgt,
                                             const float* __restrict__ partial,
                                             const float* __restrict__ W,
                                             float* __restrict__ out) {
  const int b = blockIdx.y;
  const int o0 = blockIdx.x * 128;
  __shared__ float c[KK];
  __shared__ float red[4][128];
  for (int k = threadIdx.x; k < KK; k += 256) {
    float v;
    if (k < DD) {
      v = tgt[(size_t)b * DD + k];
    } else {
      const int d = k - DD;
      v = 0.f;
      for (int pp = 0; pp < NSPLIT; ++pp) v += partial[((size_t)pp * BB + b) * DD + d];
    }
    c[k] = v;
  }
  __syncthreads();
  const int ks = threadIdx.x >> 6;   // k-quarter
  const int ol = threadIdx.x & 63;   // o-pair lane
  float acc0 = 0.f, acc1 = 0.f;
  const float* wp = W + o0 + ol * 2;
  for (int k = ks * 512; k < ks * 512 + 512; ++k) {
    float2 wv = *(const float2*)(wp + (size_t)k * OO);
    float ck = c[k];
    acc0 += ck * wv.x; acc1 += ck * wv.y;
  }
  red[ks][ol * 2] = acc0;
  red[ks][ol * 2 + 1] = acc1;
  __syncthreads();
  if (threadIdx.x < 128) {
    float s = red[0][threadIdx.x] + red[1][threadIdx.x] + red[2][threadIdx.x] + red[3][threadIdx.x];
    out[(size_t)b * OO + o0 + threadIdx.x] = tanhf(s);
  }
}

extern "C" void kernel_launch(void* const* d_in, const int* in_sizes, int n_in,
                              void* d_out, int out_size, void* d_ws, size_t ws_size,
                              hipStream_t stream) {
  const float* src = (const float*)d_in[0];
  const float* tgt = (const float*)d_in[1];
  const int* pos   = (const int*)d_in[2];
  const float* W   = (const float*)d_in[3];
  float* out = (float*)d_out;

  float* ws      = (float*)d_ws;
  float* score   = ws;                       // B*S        = 131072 floats
  float* stats   = score + (size_t)BB * SS;  // 2*B        = 64 floats
  float* partial = stats + 2 * BB;           // NSPLIT*B*D = 262144 floats

  k_score   <<<dim3(SS / 16, BB), 256, 0, stream>>>(src, tgt, score);
  k_stats   <<<BB,                256, 0, stream>>>(score, stats);
  k_weighted<<<dim3(NSPLIT, BB),  256, 0, stream>>>(src, score, stats, pos, partial);
  k_out     <<<dim3(OO / 128, BB), 256, 0, stream>>>(tgt, partial, W, out);
}